// Round 7
// baseline (150.658 us; speedup 1.0000x reference)
//
#include <hip/hip_runtime.h>
#include <math.h>

#define N_G   64
#define M_N   32
#define FEAT  256
#define POSD  6
#define D     262
#define MSG   128
#define NCLS  7

#define KHW   288       // weight K window over h (262 -> 288)
#define KFULL 416       // full concat K [mv 128 | h 288]
#define HSTR  416       // G_H row stride (shorts): [mv 128 | h 262 | pad 26]
#define PSTR  320       // G_PA/G_PB row stride (shorts)

// packed weight sizes (shorts)
#define S_PROJ (528*288)
#define S_MSG  (128*288)
#define S_RZ   (544*416)
#define S_XN   (272*128)
#define S_HN   (272*288)
#define S_RO   (128*288)
#define S_RO2  (16*128)

// workspace float offsets — weights (as before) then staged activations
#define O_WPROJ 0u
#define O_WMSG  76032u
#define O_WRZ   94464u
#define O_WXN   207616u
#define O_WHN   225024u
#define O_WRO   264192u
#define O_WRO2  282624u
#define O_GB    283648u      // 1088 fp32 gate biases
#define O_GHA   284736u      // [64][32][416] bf16  h-state buf A
#define O_GHB   710720u      // [64][32][416] bf16  h-state buf B
#define O_GPA   1136704u     // [64][32][320] bf16  proj-a
#define O_GPB   1464384u     // [64][32][320] bf16  proj-b
#define O_GATT  1792064u     // [64][32][40]  bf16  att (A-layout for mix)
#define O_GMSG  1833024u     // [64][128][40] bf16  msg0 (B^T layout)
#define O_B1P   1996864u     // [320] f32 padded link_b1
#define O_W2P   1997184u     // [320] f32 padded link_w2
// end: 1997504 floats ~ 7.6 MB

typedef __attribute__((ext_vector_type(8))) short short8;
typedef __attribute__((ext_vector_type(4))) short short4v;
typedef __attribute__((ext_vector_type(4))) float floatx4;

#define MFMA __builtin_amdgcn_mfma_f32_16x16x32_bf16

__device__ __forceinline__ short f2bf(float f) {
    union { float f; unsigned u; } v; v.f = f;
    unsigned r = v.u + 0x7FFF + ((v.u >> 16) & 1);   // RNE
    return (short)(r >> 16);
}
__device__ __forceinline__ float bf2f(short s) {
    union { float f; unsigned u; } v;
    v.u = ((unsigned)(unsigned short)s) << 16;
    return v.f;
}
__device__ __forceinline__ float sigf(float x) {
    return __builtin_amdgcn_rcpf(1.f + __expf(-x));
}
__device__ __forceinline__ float tanh_fast(float x) {
    float e = __expf(-2.f * fabsf(x));
    float t = (1.f - e) * __builtin_amdgcn_rcpf(1.f + e);
    return copysignf(t, x);
}

// ---------------------------------------------------------------------------
// prep: row-per-wave weight pack + h0 init + pad zeroing + padded b1/w2.
// jobs: 0..1891 weights | 1892 b1/w2 | 1893..3940 h0-init | 3941..5988 padzero
// ---------------------------------------------------------------------------
__global__ __launch_bounds__(256) void prep_kernel(
    const float* __restrict__ w1, const float* __restrict__ msg_w,
    const float* __restrict__ w_ih, const float* __restrict__ w_hh,
    const float* __restrict__ ro_w1, const float* __restrict__ ro_w2,
    const float* __restrict__ b_ih, const float* __restrict__ b_hh,
    const float* __restrict__ b1g, const float* __restrict__ w2g,
    const float* __restrict__ nodes, const float* __restrict__ pos,
    float* __restrict__ ws)
{
    short* wproj = (short*)(ws + O_WPROJ);
    short* wmsg  = (short*)(ws + O_WMSG);
    short* wrz   = (short*)(ws + O_WRZ);
    short* wxn   = (short*)(ws + O_WXN);
    short* whn   = (short*)(ws + O_WHN);
    short* wro   = (short*)(ws + O_WRO);
    short* wro2  = (short*)(ws + O_WRO2);
    float* gb    = ws + O_GB;

    int row = blockIdx.x * 4 + (threadIdx.x >> 6);
    const int lane = threadIdx.x & 63;
    if (row >= 5989) return;

    if (row < 528) {                              // wproj [528][288]
        const int n = row;
        short* out = wproj + n * 288;
        const float* src = (n < D) ? (w1 + n * 524) : (w1 + (n - D) * 524 + D);
        for (int k = lane; k < 288; k += 64)
            out[k] = f2bf((k < D && n < 524) ? src[k] : 0.f);
        return;
    }
    row -= 528;
    if (row < 128) {                              // wmsg [128][288]
        short* out = wmsg + row * 288;
        const float* src = msg_w + row * D;
        for (int k = lane; k < 288; k += 64)
            out[k] = f2bf(k < D ? src[k] : 0.f);
        return;
    }
    row -= 128;
    if (row < 544) {                              // wrz [544][416]
        const int g = row;
        const int gi = (g < 272) ? 0 : 1;
        const int d = g - gi * 272;
        short* out = wrz + g * 416;
        if (d < D) {
            const int r = gi * D + d;
            const float* sih = w_ih + r * MSG;
            const float* shh = w_hh + r * D - 128;
            for (int k = lane; k < 416; k += 64) {
                float v;
                if (k < 128)            v = sih[k];
                else if (k < 128 + D)   v = shh[k];
                else                    v = 0.f;
                out[k] = f2bf(v);
            }
        } else {
            for (int k = lane; k < 416; k += 64) out[k] = 0;
        }
        return;
    }
    row -= 544;
    if (row < 272) {                              // wxn [272][128]
        const int d = row;
        short* out = wxn + d * 128;
        const float* src = w_ih + (2 * D + d) * MSG;
        for (int k = lane; k < 128; k += 64)
            out[k] = f2bf(d < D ? src[k] : 0.f);
        return;
    }
    row -= 272;
    if (row < 272) {                              // whn [272][288]
        const int d = row;
        short* out = whn + d * 288;
        const float* src = w_hh + (2 * D + d) * D;
        for (int k = lane; k < 288; k += 64)
            out[k] = f2bf((d < D && k < D) ? src[k] : 0.f);
        return;
    }
    row -= 272;
    if (row < 128) {                              // wro [128][288]
        short* out = wro + row * 288;
        const float* src = ro_w1 + row * D;
        for (int k = lane; k < 288; k += 64)
            out[k] = f2bf(k < D ? src[k] : 0.f);
        return;
    }
    row -= 128;
    if (row < 16) {                               // wro2 [16][128]
        short* out = wro2 + row * 128;
        const float* src = ro_w2 + row * MSG;
        for (int k = lane; k < 128; k += 64)
            out[k] = f2bf(row < NCLS ? src[k] : 0.f);
        return;
    }
    row -= 16;
    if (row < 4) {                                // gate biases [4][272]
        const int seg = row;
        float* out = gb + seg * 272;
        for (int d = lane; d < 272; d += 64) {
            float v = 0.f;
            if (d < D) {
                if (seg == 0)      v = b_ih[d] + b_hh[d];
                else if (seg == 1) v = b_ih[D + d] + b_hh[D + d];
                else if (seg == 2) v = b_ih[2 * D + d];
                else               v = b_hh[2 * D + d];
            }
            out[d] = v;
        }
        return;
    }
    row -= 4;
    if (row < 1) {                                // padded b1/w2 [320] f32
        float* b1p = ws + O_B1P;
        float* w2p = ws + O_W2P;
        for (int k = lane; k < 320; k += 64) {
            b1p[k] = (k < D) ? b1g[k] : 0.f;
            w2p[k] = (k < D) ? w2g[k] : 0.f;
        }
        return;
    }
    row -= 1;
    if (row < 2048) {                             // h0 init -> G_HA h-part
        const int b = row >> 5, w = row & 31;
        short* out = (short*)(ws + O_GHA) + (size_t)(b * 32 + w) * HSTR + 128;
        const float* nsrc = nodes + (size_t)(b * 32 + w) * FEAT;
        const float* psrc = pos + (size_t)(b * 32 + w) * POSD;
        for (int k = lane; k < 288; k += 64) {
            float v = 0.f;
            if (k < FEAT)             v = nsrc[k];
            else if (k < FEAT + POSD) v = psrc[k - FEAT];
            out[k] = f2bf(v);
        }
        return;
    }
    row -= 2048;
    {                                             // pad zeroing (2048 rows)
        const int b = row >> 5, w = row & 31;
        short* hb = (short*)(ws + O_GHB) + (size_t)(b * 32 + w) * HSTR + 128;
        short* pa = (short*)(ws + O_GPA) + (size_t)(b * 32 + w) * PSTR;
        short* pb = (short*)(ws + O_GPB) + (size_t)(b * 32 + w) * PSTR;
        if (lane < 26) hb[D + lane] = 0;          // G_HB h pads 262..287
        if (lane < 58) { pa[D + lane] = 0; pb[D + lane] = 0; }   // 262..319
    }
}

// ---------------------------------------------------------------------------
// k_proj: proj (tiles 0..32) + round-0 msg (33..40). 2624 tile-waves.
// ---------------------------------------------------------------------------
__global__ __launch_bounds__(256, 2) void k_proj(
    const float* __restrict__ ws, const float* __restrict__ msg_bg)
{
    const short* GH   = (const short*)(ws + O_GHA);
    short* GPA        = (short*)(ws + O_GPA);
    short* GPB        = (short*)(ws + O_GPB);
    short* GMSG       = (short*)(ws + O_GMSG);
    const short* Wproj = (const short*)(ws + O_WPROJ);
    const short* Wmsg  = (const short*)(ws + O_WMSG);

    const int job = blockIdx.x * 4 + (threadIdx.x >> 6);   // 656*4 = 2624 exact
    const int b = job / 41, t = job % 41;
    const int lane = threadIdx.x & 63;
    const int quad = lane >> 4, lrow = lane & 15;

    const short* ap0 = GH + (size_t)(b * 32 + lrow) * HSTR + 128 + quad * 8;
    const short* ap1 = ap0 + 16 * HSTR;
    const short* bw = (t < 33)
        ? Wproj + (t * 16 + lrow) * KHW + quad * 8
        : Wmsg + ((t - 33) * 16 + lrow) * KHW + quad * 8;

    short8 a0[9], a1[9], wv[9];
#pragma unroll
    for (int kk = 0; kk < 9; ++kk) {
        a0[kk] = *(const short8*)(ap0 + kk * 32);
        a1[kk] = *(const short8*)(ap1 + kk * 32);
        wv[kk] = *(const short8*)(bw + kk * 32);
    }
    floatx4 acc0 = {}, acc1 = {};
#pragma unroll
    for (int kk = 0; kk < 9; ++kk) {
        acc0 = MFMA(a0[kk], wv[kk], acc0, 0, 0, 0);
        acc1 = MFMA(a1[kk], wv[kk], acc1, 0, 0, 0);
    }
    if (t < 33) {
        int col = t * 16 + lrow;
#pragma unroll
        for (int rr = 0; rr < 4; ++rr) {
            int r0 = quad * 4 + rr;
            if (col < D) {
                GPA[(size_t)(b * 32 + r0) * PSTR + col] = f2bf(acc0[rr]);
                GPA[(size_t)(b * 32 + r0 + 16) * PSTR + col] = f2bf(acc1[rr]);
            } else if (col < 2 * D) {
                GPB[(size_t)(b * 32 + r0) * PSTR + (col - D)] = f2bf(acc0[rr]);
                GPB[(size_t)(b * 32 + r0 + 16) * PSTR + (col - D)] = f2bf(acc1[rr]);
            }
        }
    } else {
        int col = (t - 33) * 16 + lrow;
        float bias = msg_bg[col];
#pragma unroll
        for (int rr = 0; rr < 4; ++rr) {
            GMSG[(size_t)b * 5120 + col * 40 + quad * 4 + rr] = f2bf(acc0[rr] + bias);
            GMSG[(size_t)b * 5120 + col * 40 + 16 + quad * 4 + rr] = f2bf(acc1[rr] + bias);
        }
    }
}

// ---------------------------------------------------------------------------
// k_att: 4096 groups of 16 lanes: (graph, receiver i, j-half) each 16 j's.
// ---------------------------------------------------------------------------
__global__ __launch_bounds__(256, 4) void k_att(
    const float* __restrict__ ws, const int* __restrict__ nrec_g,
    const float* __restrict__ b2g, float* __restrict__ att_out)
{
    const short* GPA = (const short*)(ws + O_GPA);
    const short* GPB = (const short*)(ws + O_GPB);
    short* GATT      = (short*)(ws + O_GATT);
    const float* b1p = ws + O_B1P;
    const float* w2p = ws + O_W2P;

    const int g = blockIdx.x * 16 + (threadIdx.x >> 4);    // 0..4095
    const int b = g >> 6;
    const int rem = g & 63;
    const int i = rem >> 1, jh = (rem & 1) * 16;
    const int c16 = threadIdx.x & 15;
    const int nr = nrec_g[b];
    const float b2v = b2g[0];

    float pav[5][4], b1v[5][4], w2v[5][4];
#pragma unroll
    for (int k = 0; k < 5; ++k) {
        int dbase = c16 * 4 + 64 * k;
        short4v p = *(const short4v*)(GPA + (size_t)(b * 32 + i) * PSTR + dbase);
        floatx4 bb = *(const floatx4*)(b1p + dbase);
        floatx4 ww = *(const floatx4*)(w2p + dbase);
#pragma unroll
        for (int e = 0; e < 4; ++e) {
            pav[k][e] = bf2f(p[e]); b1v[k][e] = bb[e]; w2v[k][e] = ww[e];
        }
    }
    float p0 = 0.f;
#pragma unroll
    for (int k = 0; k < 5; ++k)
#pragma unroll
        for (int e = 0; e < 4; ++e)
            p0 += fmaxf(b1v[k][e], 0.f) * w2v[k][e];
    p0 += __shfl_down(p0, 8, 16); p0 += __shfl_down(p0, 4, 16);
    p0 += __shfl_down(p0, 2, 16); p0 += __shfl_down(p0, 1, 16);
    float c0 = sigf(p0 + b2v);
    const bool vi = i < nr;
    for (int jj = 0; jj < 16; ++jj) {
        int j = jh + jj;
        float a;
        if (j < nr && vi) {
            const short* pb = GPB + (size_t)(b * 32 + j) * PSTR + c16 * 4;
            float s = 0.f;
#pragma unroll
            for (int k = 0; k < 5; ++k) {
                short4v q = *(const short4v*)(pb + 64 * k);
#pragma unroll
                for (int e = 0; e < 4; ++e) {
                    float v = pav[k][e] + bf2f(q[e]) + b1v[k][e];
                    s += fmaxf(v, 0.f) * w2v[k][e];
                }
            }
            s += __shfl_down(s, 8, 16); s += __shfl_down(s, 4, 16);
            s += __shfl_down(s, 2, 16); s += __shfl_down(s, 1, 16);
            a = sigf(s + b2v);
        } else {
            a = c0;
        }
        if (c16 == 0) {
            att_out[((size_t)(b * 32 + i)) * 32 + j] = a;
            GATT[(size_t)b * 1280 + i * 40 + j] = f2bf((j < nr) ? a : 0.f);
        }
    }
}

// ---------------------------------------------------------------------------
// k_mix0: mv = att @ msg0 -> G_HA mv cols. 64 blocks x 4 waves (ng each).
// ---------------------------------------------------------------------------
__global__ __launch_bounds__(256, 4) void k_mix0(float* __restrict__ ws)
{
    const short* GATT = (const short*)(ws + O_GATT);
    const short* GMSG = (const short*)(ws + O_GMSG);
    short* GH         = (short*)(ws + O_GHA);

    const int b = blockIdx.x;
    const int tid = threadIdx.x;
    const int ng = tid >> 6, lane = tid & 63;
    const int quad = lane >> 4, lrow = lane & 15;

    short8 af0 = *(const short8*)(GATT + (size_t)b * 1280 + lrow * 40 + quad * 8);
    short8 af1 = *(const short8*)(GATT + (size_t)b * 1280 + (16 + lrow) * 40 + quad * 8);
    short8 bf0 = *(const short8*)(GMSG + (size_t)b * 5120 + (ng * 32 + lrow) * 40 + quad * 8);
    short8 bf1 = *(const short8*)(GMSG + (size_t)b * 5120 + (ng * 32 + 16 + lrow) * 40 + quad * 8);
    floatx4 c00 = {}, c01 = {}, c10 = {}, c11 = {};
    c00 = MFMA(af0, bf0, c00, 0, 0, 0);
    c01 = MFMA(af0, bf1, c01, 0, 0, 0);
    c10 = MFMA(af1, bf0, c10, 0, 0, 0);
    c11 = MFMA(af1, bf1, c11, 0, 0, 0);
#pragma unroll
    for (int rr = 0; rr < 4; ++rr) {
        int m0 = quad * 4 + rr;
        GH[(size_t)(b * 32 + m0) * HSTR + ng * 32 + lrow] = f2bf(c00[rr]);
        GH[(size_t)(b * 32 + m0) * HSTR + ng * 32 + 16 + lrow] = f2bf(c01[rr]);
        GH[(size_t)(b * 32 + m0 + 16) * HSTR + ng * 32 + lrow] = f2bf(c10[rr]);
        GH[(size_t)(b * 32 + m0 + 16) * HSTR + ng * 32 + 16 + lrow] = f2bf(c11[rr]);
    }
}

// ---------------------------------------------------------------------------
// k_gru: 1088 tile-waves (64 graphs x 17 d-tiles), src/dst global H bufs.
// ---------------------------------------------------------------------------
__global__ __launch_bounds__(256, 2) void k_gru(
    float* __restrict__ ws, const int* __restrict__ nrec_g, const int srcA)
{
    const short* src = (const short*)(ws + (srcA ? O_GHA : O_GHB));
    short* dst       = (short*)(ws + (srcA ? O_GHB : O_GHA));
    const short* Wrz = (const short*)(ws + O_WRZ);
    const short* Wxn = (const short*)(ws + O_WXN);
    const short* Whn = (const short*)(ws + O_WHN);
    const float* gb  = ws + O_GB;

    const int job = blockIdx.x * 4 + (threadIdx.x >> 6);   // 272*4 = 1088 exact
    const int b = job / 17, s = job % 17;
    const int nr = nrec_g[b];
    const int lane = threadIdx.x & 63;
    const int quad = lane >> 4, lrow = lane & 15;

    const short* ap0 = src + (size_t)(b * 32 + lrow) * HSTR + quad * 8;
    const short* ap1 = ap0 + 16 * HSTR;
    short8 aA0[13], aA1[13];
#pragma unroll
    for (int kk = 0; kk < 13; ++kk) {
        aA0[kk] = *(const short8*)(ap0 + kk * 32);
        aA1[kk] = *(const short8*)(ap1 + kk * 32);
    }
    const short* bpr = Wrz + (s * 16 + lrow) * KFULL + quad * 8;
    const short* bpz = bpr + 272 * KFULL;
    const short* bpx = Wxn + (s * 16 + lrow) * 128 + quad * 8;
    const short* bph = Whn + (s * 16 + lrow) * KHW + quad * 8;

    short8 wr[13];
#pragma unroll
    for (int kk = 0; kk < 13; ++kk) wr[kk] = *(const short8*)(bpr + kk * 32);

    floatx4 aR0 = {}, aR1 = {}, aZ0 = {}, aZ1 = {};
    floatx4 aN0 = {}, aN1 = {}, aH0 = {}, aH1 = {};
#pragma unroll
    for (int kk = 0; kk < 13; ++kk) {           // r (+x inline); stage z
        aR0 = MFMA(aA0[kk], wr[kk], aR0, 0, 0, 0);
        aR1 = MFMA(aA1[kk], wr[kk], aR1, 0, 0, 0);
        if (kk < 4) {
            short8 bx = *(const short8*)(bpx + kk * 32);
            aN0 = MFMA(aA0[kk], bx, aN0, 0, 0, 0);
            aN1 = MFMA(aA1[kk], bx, aN1, 0, 0, 0);
        }
        wr[kk] = *(const short8*)(bpz + kk * 32);
    }
#pragma unroll
    for (int kk = 0; kk < 13; ++kk) {           // z chain; stage h
        aZ0 = MFMA(aA0[kk], wr[kk], aZ0, 0, 0, 0);
        aZ1 = MFMA(aA1[kk], wr[kk], aZ1, 0, 0, 0);
        if (kk < 9) wr[kk] = *(const short8*)(bph + kk * 32);
    }
#pragma unroll
    for (int kk = 0; kk < 9; ++kk) {            // h chain
        aH0 = MFMA(aA0[kk + 4], wr[kk], aH0, 0, 0, 0);
        aH1 = MFMA(aA1[kk + 4], wr[kk], aH1, 0, 0, 0);
    }

    const int d = s * 16 + lrow;
    if (d < D) {
        float bgr = gb[d], bgz = gb[272 + d];
        float bxv = gb[544 + d], bhv = gb[816 + d];
#pragma unroll
        for (int i = 0; i < 2; ++i) {
            floatx4 vR = i ? aR1 : aR0, vZ = i ? aZ1 : aZ0;
            floatx4 vN = i ? aN1 : aN0, vH = i ? aH1 : aH0;
#pragma unroll
            for (int rr = 0; rr < 4; ++rr) {
                int m = i * 16 + quad * 4 + rr;
                float rg = sigf(vR[rr] + bgr);
                float zg = sigf(vZ[rr] + bgz);
                float cg = tanh_fast(vN[rr] + bxv + rg * (vH[rr] + bhv));
                float hold = bf2f(src[(size_t)(b * 32 + m) * HSTR + 128 + d]);
                float hv = (1.f - zg) * cg + zg * hold;
                if (m >= nr) hv = 0.f;
                dst[(size_t)(b * 32 + m) * HSTR + 128 + d] = f2bf(hv);
            }
        }
    }
}

// ---------------------------------------------------------------------------
// k_msgmix1: msg1 = h1 @ Wmsg^T (LDS) then mv1 = att @ msg1 -> G_HB mv.
// ---------------------------------------------------------------------------
__global__ __launch_bounds__(256, 2) void k_msgmix1(
    float* __restrict__ ws, const float* __restrict__ msg_bg)
{
    __shared__ __align__(16) short msgT[128 * 40];
    short* GHB        = (short*)(ws + O_GHB);
    const short* GATT = (const short*)(ws + O_GATT);
    const short* Wmsg = (const short*)(ws + O_WMSG);

    const int b = blockIdx.x;
    const int tid = threadIdx.x;
    const int wave = tid >> 6, lane = tid & 63;
    const int quad = lane >> 4, lrow = lane & 15;

    const short* ap0 = GHB + (size_t)(b * 32 + lrow) * HSTR + 128 + quad * 8;
    const short* ap1 = ap0 + 16 * HSTR;
    short8 a0[9], a1[9];
#pragma unroll
    for (int kk = 0; kk < 9; ++kk) {
        a0[kk] = *(const short8*)(ap0 + kk * 32);
        a1[kk] = *(const short8*)(ap1 + kk * 32);
    }
#pragma unroll
    for (int ti = 0; ti < 2; ++ti) {
        int s = wave + ti * 4;
        const short* bw = Wmsg + (s * 16 + lrow) * KHW + quad * 8;
        short8 wv[9];
#pragma unroll
        for (int kk = 0; kk < 9; ++kk) wv[kk] = *(const short8*)(bw + kk * 32);
        floatx4 acc0 = {}, acc1 = {};
#pragma unroll
        for (int kk = 0; kk < 9; ++kk) {
            acc0 = MFMA(a0[kk], wv[kk], acc0, 0, 0, 0);
            acc1 = MFMA(a1[kk], wv[kk], acc1, 0, 0, 0);
        }
        int col = s * 16 + lrow;
        float bias = msg_bg[col];
#pragma unroll
        for (int rr = 0; rr < 4; ++rr) {
            msgT[col * 40 + quad * 4 + rr] = f2bf(acc0[rr] + bias);
            msgT[col * 40 + 16 + quad * 4 + rr] = f2bf(acc1[rr] + bias);
        }
    }
    __syncthreads();
    {
        const int ng = wave;
        short8 af0 = *(const short8*)(GATT + (size_t)b * 1280 + lrow * 40 + quad * 8);
        short8 af1 = *(const short8*)(GATT + (size_t)b * 1280 + (16 + lrow) * 40 + quad * 8);
        short8 bf0 = *(const short8*)(msgT + (ng * 32 + lrow) * 40 + quad * 8);
        short8 bf1 = *(const short8*)(msgT + (ng * 32 + 16 + lrow) * 40 + quad * 8);
        floatx4 c00 = {}, c01 = {}, c10 = {}, c11 = {};
        c00 = MFMA(af0, bf0, c00, 0, 0, 0);
        c01 = MFMA(af0, bf1, c01, 0, 0, 0);
        c10 = MFMA(af1, bf0, c10, 0, 0, 0);
        c11 = MFMA(af1, bf1, c11, 0, 0, 0);
#pragma unroll
        for (int rr = 0; rr < 4; ++rr) {
            int m0 = quad * 4 + rr;
            GHB[(size_t)(b * 32 + m0) * HSTR + ng * 32 + lrow] = f2bf(c00[rr]);
            GHB[(size_t)(b * 32 + m0) * HSTR + ng * 32 + 16 + lrow] = f2bf(c01[rr]);
            GHB[(size_t)(b * 32 + m0 + 16) * HSTR + ng * 32 + lrow] = f2bf(c10[rr]);
            GHB[(size_t)(b * 32 + m0 + 16) * HSTR + ng * 32 + 16 + lrow] = f2bf(c11[rr]);
        }
    }
}

// ---------------------------------------------------------------------------
// k_out: readout GEMM (LDS hid) + final pred. 64 blocks x 4 waves.
// ---------------------------------------------------------------------------
__global__ __launch_bounds__(256, 2) void k_out(
    const float* __restrict__ ws, const int* __restrict__ nrec_g,
    const float* __restrict__ ro_b1g, const float* __restrict__ ro_b2g,
    float* __restrict__ pred)
{
    __shared__ __align__(16) short hidL[32 * 136];
    const short* GHA  = (const short*)(ws + O_GHA);
    const short* Wro  = (const short*)(ws + O_WRO);
    const short* Wro2 = (const short*)(ws + O_WRO2);

    const int b = blockIdx.x;
    const int tid = threadIdx.x;
    const int wave = tid >> 6, lane = tid & 63;
    const int quad = lane >> 4, lrow = lane & 15;
    const int nr = nrec_g[b];

    const short* ap0 = GHA + (size_t)(b * 32 + lrow) * HSTR + 128 + quad * 8;
    const short* ap1 = ap0 + 16 * HSTR;
    short8 a0[9], a1[9];
#pragma unroll
    for (int kk = 0; kk < 9; ++kk) {
        a0[kk] = *(const short8*)(ap0 + kk * 32);
        a1[kk] = *(const short8*)(ap1 + kk * 32);
    }
#pragma unroll
    for (int ti = 0; ti < 2; ++ti) {
        int s = wave + ti * 4;
        const short* bw = Wro + (s * 16 + lrow) * KHW + quad * 8;
        short8 wv[9];
#pragma unroll
        for (int kk = 0; kk < 9; ++kk) wv[kk] = *(const short8*)(bw + kk * 32);
        floatx4 acc0 = {}, acc1 = {};
#pragma unroll
        for (int kk = 0; kk < 9; ++kk) {
            acc0 = MFMA(a0[kk], wv[kk], acc0, 0, 0, 0);
            acc1 = MFMA(a1[kk], wv[kk], acc1, 0, 0, 0);
        }
        int col = s * 16 + lrow;
        float bias = ro_b1g[col];
#pragma unroll
        for (int rr = 0; rr < 4; ++rr) {
            hidL[(quad * 4 + rr) * 136 + col] = f2bf(fmaxf(acc0[rr] + bias, 0.f));
            hidL[(16 + quad * 4 + rr) * 136 + col] = f2bf(fmaxf(acc1[rr] + bias, 0.f));
        }
    }
    __syncthreads();
    if (wave == 0) {
        const short* bw = Wro2 + lrow * 128 + quad * 8;
        short8 wv[4];
#pragma unroll
        for (int kk = 0; kk < 4; ++kk) wv[kk] = *(const short8*)(bw + kk * 32);
        floatx4 acc0 = {}, acc1 = {};
        const short* ap = hidL + lrow * 136 + quad * 8;
#pragma unroll
        for (int kk = 0; kk < 4; ++kk) {
            short8 x0 = *(const short8*)(ap + kk * 32);
            short8 x1 = *(const short8*)(ap + 16 * 136 + kk * 32);
            acc0 = MFMA(x0, wv[kk], acc0, 0, 0, 0);
            acc1 = MFMA(x1, wv[kk], acc1, 0, 0, 0);
        }
        int q = lrow;
        if (q < NCLS) {
            float bias = ro_b2g[q];
#pragma unroll
            for (int i = 0; i < 2; ++i) {
#pragma unroll
                for (int rr = 0; rr < 4; ++rr) {
                    int m = i * 16 + quad * 4 + rr;
                    float v = (i ? acc1[rr] : acc0[rr]) + bias;
                    if (m >= nr) v = 0.f;
                    pred[((size_t)(b * 32 + m)) * NCLS + q] = v;
                }
            }
        }
    }
}

// ---------------------------------------------------------------------------
extern "C" void kernel_launch(void* const* d_in, const int* in_sizes, int n_in,
                              void* d_out, int out_size, void* d_ws, size_t ws_size,
                              hipStream_t stream)
{
    const float* nodes = (const float*)d_in[0];
    const float* pos   = (const float*)d_in[1];
    const int*   nrec  = (const int*)d_in[2];
    const float* w1    = (const float*)d_in[3];
    const float* b1    = (const float*)d_in[4];
    const float* w2    = (const float*)d_in[5];
    const float* b2    = (const float*)d_in[6];
    const float* msg_w = (const float*)d_in[7];
    const float* msg_b = (const float*)d_in[8];
    const float* w_ih  = (const float*)d_in[9];
    const float* w_hh  = (const float*)d_in[10];
    const float* b_ih  = (const float*)d_in[11];
    const float* b_hh  = (const float*)d_in[12];
    const float* ro_w1 = (const float*)d_in[13];
    const float* ro_b1 = (const float*)d_in[14];
    const float* ro_w2 = (const float*)d_in[15];
    const float* ro_b2 = (const float*)d_in[16];
    float* ws   = (float*)d_ws;
    float* pred = (float*)d_out;
    float* attout = pred + (size_t)N_G * M_N * NCLS;

    prep_kernel<<<1498, 256, 0, stream>>>(w1, msg_w, w_ih, w_hh, ro_w1, ro_w2,
                                          b_ih, b_hh, b1, w2, nodes, pos, ws);
    k_proj<<<656, 256, 0, stream>>>(ws, msg_b);
    k_att<<<256, 256, 0, stream>>>(ws, nrec, b2, attout);
    k_mix0<<<64, 256, 0, stream>>>(ws);
    k_gru<<<272, 256, 0, stream>>>(ws, nrec, 1);
    k_msgmix1<<<64, 256, 0, stream>>>(ws, msg_b);
    k_gru<<<272, 256, 0, stream>>>(ws, nrec, 0);
    k_out<<<64, 256, 0, stream>>>(ws, nrec, ro_b1, ro_b2, pred);
}